// Round 8
// baseline (353.898 us; speedup 1.0000x reference)
//
#include <hip/hip_runtime.h>
#include <hip/hip_bf16.h>

// ---------- types ----------
typedef __attribute__((ext_vector_type(8))) short s16x8;   // 8 bf16 (4 VGPR)
typedef __attribute__((ext_vector_type(4))) short s16x4;   // 4 bf16
typedef __attribute__((ext_vector_type(4))) float f32x4;

#define MFMA16(a, b, c) __builtin_amdgcn_mfma_f32_16x16x32_bf16(a, b, c, 0, 0, 0)

__device__ __forceinline__ short f2bf(float f) {
  unsigned int x = __builtin_bit_cast(unsigned int, f);
  x += 0x7fffu + ((x >> 16) & 1u);   // RNE; inputs always finite here
  return (short)(x >> 16);
}

// fragment permutation within a 32-block: element with true index k stored at
// c(k) = g*8 + b*4 + j for k = b*16 + g*4 + j  -> lane (r,g)'s 8 frag elems
// {4g+j, 16+4g+j} are contiguous at offset g*8 -> single b128 load.
__device__ __forceinline__ int cperm(int k) {
  return ((k & 12) << 1) | ((k >> 4) << 2) | (k & 3);
}

#define LDT 40   // padded LDS row length for GEMM tiles

// ---------- fp32 -> bf16 convert ----------
__global__ void cvt_f32_bf16(const float* __restrict__ in, short* __restrict__ out, int n) {
  int idx = blockIdx.x * blockDim.x + threadIdx.x;
  int stride = gridDim.x * blockDim.x;
  for (int i = idx * 4; i < n; i += stride * 4) {
    float4 v = *(const float4*)(in + i);
    s16x4 o;
    o[0] = f2bf(v.x); o[1] = f2bf(v.y); o[2] = f2bf(v.z); o[3] = f2bf(v.w);
    *(s16x4*)(out + i) = o;
  }
}

// ---------- GEMM1: qkv = Xb @ Wqkv + b ----------
// Q: [bn][s][h-cperm], pre-scaled by 0.125*log2(e) (exp2-domain softmax)
// K: [bn][s][h-cperm]
// V: [bn][h][s-cperm]  (transposed per head, kv-dim cperm'd)
__global__ __launch_bounds__(256) void gemm_qkv(
    const short* __restrict__ X, const short* __restrict__ W,
    const float* __restrict__ bias,
    short* __restrict__ Qo, short* __restrict__ Ko, short* __restrict__ Vo) {
  const int N = 3072, Kd = 1024;
  __shared__ short As[128 * LDT];
  __shared__ short Bs[128 * LDT];
  int t = threadIdx.x;
  int nTN = N / 128;
  int m0 = (blockIdx.x / nTN) * 128;
  int n0 = (blockIdx.x % nTN) * 128;
  int lane = t & 63, w = t >> 6;
  int wr = (w >> 1) * 64, wc = (w & 1) * 64;
  int r = lane & 15, g = lane >> 4;

  int ar = t >> 1;
  int ak = (t & 1) << 4;
  int bk = t & 31;
  int bc = (t >> 5) << 4;
  int cbk = cperm(bk);

  f32x4 acc[4][4];
  const f32x4 z4 = {0.f, 0.f, 0.f, 0.f};
#pragma unroll
  for (int i = 0; i < 4; ++i)
#pragma unroll
    for (int j = 0; j < 4; ++j) acc[i][j] = z4;

  for (int kt = 0; kt < Kd; kt += 32) {
    if (kt) __syncthreads();
    const short* xr = X + (size_t)(m0 + ar) * Kd + kt + ak;
    s16x8 va0 = *(const s16x8*)(xr);
    s16x8 va1 = *(const s16x8*)(xr + 8);
    short* Ad = &As[ar * LDT];
    *(s16x4*)(Ad + cperm(ak))      = __builtin_shufflevector(va0, va0, 0, 1, 2, 3);
    *(s16x4*)(Ad + cperm(ak + 4))  = __builtin_shufflevector(va0, va0, 4, 5, 6, 7);
    *(s16x4*)(Ad + cperm(ak + 8))  = __builtin_shufflevector(va1, va1, 0, 1, 2, 3);
    *(s16x4*)(Ad + cperm(ak + 12)) = __builtin_shufflevector(va1, va1, 4, 5, 6, 7);
    const short* wrp = W + (size_t)(kt + bk) * N + n0 + bc;
    s16x8 vb0 = *(const s16x8*)(wrp);
    s16x8 vb1 = *(const s16x8*)(wrp + 8);
#pragma unroll
    for (int i = 0; i < 8; ++i) Bs[(bc + i) * LDT + cbk] = vb0[i];
#pragma unroll
    for (int i = 0; i < 8; ++i) Bs[(bc + 8 + i) * LDT + cbk] = vb1[i];
    __syncthreads();

    s16x8 af[4], bfr[4];
#pragma unroll
    for (int mi = 0; mi < 4; ++mi)
      af[mi] = *(const s16x8*)(&As[(wr + mi * 16 + r) * LDT + g * 8]);
#pragma unroll
    for (int ni = 0; ni < 4; ++ni)
      bfr[ni] = *(const s16x8*)(&Bs[(wc + ni * 16 + r) * LDT + g * 8]);
#pragma unroll
    for (int mi = 0; mi < 4; ++mi)
#pragma unroll
      for (int ni = 0; ni < 4; ++ni)
        acc[mi][ni] = MFMA16(af[mi], bfr[ni], acc[mi][ni]);
  }

#pragma unroll
  for (int ni = 0; ni < 4; ++ni) {
    int col = n0 + wc + ni * 16 + r;
    float bv = bias[col];
    int which = col >> 10;
    int rem = col & 1023;
    int head = rem >> 6, h = rem & 63;
    short* dst = (which == 0) ? Qo : (which == 1) ? Ko : Vo;
    float qsc = (which == 0) ? 0.125f * 1.44269504f : 1.0f;
    int hp = (h & 32) | cperm(h & 31);   // h-dim cperm for Q/K
#pragma unroll
    for (int mi = 0; mi < 4; ++mi)
#pragma unroll
      for (int e = 0; e < 4; ++e) {
        int row = m0 + wr + mi * 16 + g * 4 + e;
        int b = row >> 11, s = row & 2047;
        size_t idx;
        if (which == 2)
          idx = ((size_t)(b * 16 + head) * 64 + h) * 2048 + ((s & ~31) | cperm(s & 31));
        else
          idx = ((size_t)(b * 16 + head) * 2048 + s) * 64 + hp;
        dst[idx] = f2bf((acc[mi][ni][e] + bv) * qsc);
      }
  }
}

// ---------- GEMM2: out = AttnOut @ Wout + b, fp32 out ----------
__global__ __launch_bounds__(256) void gemm_out(
    const short* __restrict__ X, const short* __restrict__ W,
    const float* __restrict__ bias, float* __restrict__ Out) {
  const int N = 1024, Kd = 1024;
  __shared__ short As[128 * LDT];
  __shared__ short Bs[128 * LDT];
  int t = threadIdx.x;
  int nTN = N / 128;
  int m0 = (blockIdx.x / nTN) * 128;
  int n0 = (blockIdx.x % nTN) * 128;
  int lane = t & 63, w = t >> 6;
  int wr = (w >> 1) * 64, wc = (w & 1) * 64;
  int r = lane & 15, g = lane >> 4;
  int ar = t >> 1, ak = (t & 1) << 4;
  int bk = t & 31, bc = (t >> 5) << 4;
  int cbk = cperm(bk);

  f32x4 acc[4][4];
  const f32x4 z4 = {0.f, 0.f, 0.f, 0.f};
#pragma unroll
  for (int i = 0; i < 4; ++i)
#pragma unroll
    for (int j = 0; j < 4; ++j) acc[i][j] = z4;

  for (int kt = 0; kt < Kd; kt += 32) {
    if (kt) __syncthreads();
    const short* xr = X + (size_t)(m0 + ar) * Kd + kt + ak;
    s16x8 va0 = *(const s16x8*)(xr);
    s16x8 va1 = *(const s16x8*)(xr + 8);
    short* Ad = &As[ar * LDT];
    *(s16x4*)(Ad + cperm(ak))      = __builtin_shufflevector(va0, va0, 0, 1, 2, 3);
    *(s16x4*)(Ad + cperm(ak + 4))  = __builtin_shufflevector(va0, va0, 4, 5, 6, 7);
    *(s16x4*)(Ad + cperm(ak + 8))  = __builtin_shufflevector(va1, va1, 0, 1, 2, 3);
    *(s16x4*)(Ad + cperm(ak + 12)) = __builtin_shufflevector(va1, va1, 4, 5, 6, 7);
    const short* wrp = W + (size_t)(kt + bk) * N + n0 + bc;
    s16x8 vb0 = *(const s16x8*)(wrp);
    s16x8 vb1 = *(const s16x8*)(wrp + 8);
#pragma unroll
    for (int i = 0; i < 8; ++i) Bs[(bc + i) * LDT + cbk] = vb0[i];
#pragma unroll
    for (int i = 0; i < 8; ++i) Bs[(bc + 8 + i) * LDT + cbk] = vb1[i];
    __syncthreads();

    s16x8 af[4], bfr[4];
#pragma unroll
    for (int mi = 0; mi < 4; ++mi)
      af[mi] = *(const s16x8*)(&As[(wr + mi * 16 + r) * LDT + g * 8]);
#pragma unroll
    for (int ni = 0; ni < 4; ++ni)
      bfr[ni] = *(const s16x8*)(&Bs[(wc + ni * 16 + r) * LDT + g * 8]);
#pragma unroll
    for (int mi = 0; mi < 4; ++mi)
#pragma unroll
      for (int ni = 0; ni < 4; ++ni)
        acc[mi][ni] = MFMA16(af[mi], bfr[ni], acc[mi][ni]);
  }

#pragma unroll
  for (int ni = 0; ni < 4; ++ni) {
    int col = n0 + wc + ni * 16 + r;
    float bv = bias[col];
#pragma unroll
    for (int mi = 0; mi < 4; ++mi)
#pragma unroll
      for (int e = 0; e < 4; ++e) {
        int row = m0 + wr + mi * 16 + g * 4 + e;
        Out[(size_t)row * N + col] = acc[mi][ni][e] + bv;
      }
  }
}

// ---------- causal flash attention: 2048 single-wave blocks, 33 units each ----------
// Wave (p, w) processes strip (qt=15-p, w) then strip (qt=p, 3-w):
// units = [2(15-p)+1+(w>>1)] + [2p+1+((3-w)>>1)] = 33 for EVERY wave -> no tail.
// All-register, barrier-free; K double-buffered (1 tile ahead); V issued at
// tile top (consumed after softmax). No launch-bounds cap: VGPR free to ~220.
__global__ __launch_bounds__(64) void attn(
    const short* __restrict__ Qb, const short* __restrict__ Kb,
    const short* __restrict__ Vt, short* __restrict__ Ob) {
  const int S = 2048, H = 64;
  int bid = blockIdx.x;              // 0..2047
  int bn = bid >> 5;                 // 0..63 (32 consecutive blocks share head)
  int rem = bid & 31;
  int pp = rem >> 2;                 // 0..7
  int w0 = rem & 3;                  // 0..3
  int batch = bn >> 4, head = bn & 15;
  int lane = threadIdx.x & 63;
  int r = lane & 15, g = lane >> 4;

  const short* Qh = Qb + (size_t)bn * S * H;
  const short* Kh = Kb + (size_t)bn * S * H;
  const short* Vh = Vt + (size_t)bn * S * H;   // [h][s-cperm]
  const f32x4 z4 = {0.f, 0.f, 0.f, 0.f};

  for (int sp = 0; sp < 2; ++sp) {
    int qt = sp ? pp : (15 - pp);
    int wv = sp ? (3 - w0) : w0;
    int qw = qt * 128 + wv * 32;
    int ntw = ((qw + 31) >> 6) + 1;  // 2qt+1+(wv>>1); mixed parity

    // Q fragments (B-operand [k=h][col=q]); single b128 each
    s16x8 qf[2][2];
#pragma unroll
    for (int n = 0; n < 2; ++n)
#pragma unroll
      for (int ks = 0; ks < 2; ++ks)
        qf[n][ks] = *(const s16x8*)(Qh + (size_t)(qw + n * 16 + r) * H + ks * 32 + g * 8);

    f32x4 o[2][4];
#pragma unroll
    for (int n = 0; n < 2; ++n)
#pragma unroll
      for (int hb = 0; hb < 4; ++hb) o[n][hb] = z4;
    float mrun[2] = {-__builtin_inff(), -__builtin_inff()};
    float lsum[2] = {0.f, 0.f};

    auto LOADK = [&](int kv0, s16x8 (&kf)[4][2]) {
#pragma unroll
      for (int mp = 0; mp < 4; ++mp)
#pragma unroll
        for (int ks = 0; ks < 2; ++ks)
          kf[mp][ks] = *(const s16x8*)(Kh + (size_t)(kv0 + mp * 16 + r) * H + ks * 32 + g * 8);
    };

    s16x8 kfA[4][2], kfB[4][2];
    LOADK(0, kfA);

    auto TILE = [&](int tt, s16x8 (&kfc)[4][2], s16x8 (&kfn)[4][2]) {
      int kv0 = tt * 64;
      bool need_mask = (kv0 + 63 > qw);
      int mpmax = (qw + 31 - kv0) >> 4; if (mpmax > 3) mpmax = 3;

      // V^T fragments (B-op for PV): issue first, consumed after softmax
      s16x8 vf[2][4];
#pragma unroll
      for (int kvh = 0; kvh < 2; ++kvh)
#pragma unroll
        for (int hb = 0; hb < 4; ++hb)
          vf[kvh][hb] = *(const s16x8*)(Vh + (size_t)(hb * 16 + r) * S + kv0 + kvh * 32 + g * 8);

      // prefetch K(tt+1) — consumed next tile
      int tn = tt + 1;
      if (tn < ntw) LOADK(tn * 64, kfn);

      float p[4][2][4];
      float rmax[2] = {-__builtin_inff(), -__builtin_inff()};
#pragma unroll
      for (int mp = 0; mp < 4; ++mp) {
        if (mp <= mpmax) {
          f32x4 st[2] = {z4, z4};
#pragma unroll
          for (int n = 0; n < 2; ++n)
#pragma unroll
            for (int ks = 0; ks < 2; ++ks)
              st[n] = MFMA16(kfc[mp][ks], qf[n][ks], st[n]);
#pragma unroll
          for (int n = 0; n < 2; ++n)
#pragma unroll
            for (int e = 0; e < 4; ++e) {
              float v = st[n][e];    // exp2-domain (scaled via Q)
              if (need_mask) {
                int kv = kv0 + mp * 16 + g * 4 + e;
                int q = qw + n * 16 + r;
                if (kv > q) v = -__builtin_inff();
              }
              p[mp][n][e] = v;
              rmax[n] = fmaxf(rmax[n], v);
            }
        } else {
#pragma unroll
          for (int n = 0; n < 2; ++n)
#pragma unroll
            for (int e = 0; e < 4; ++e) p[mp][n][e] = 0.f;
        }
      }

#pragma unroll
      for (int n = 0; n < 2; ++n) {
        rmax[n] = fmaxf(rmax[n], __shfl_xor(rmax[n], 16));
        rmax[n] = fmaxf(rmax[n], __shfl_xor(rmax[n], 32));
      }

      // defer-rescale (THR=8 in log2 domain)
#pragma unroll
      for (int n = 0; n < 2; ++n) {
        if (!__all(rmax[n] - mrun[n] <= 8.0f)) {
          float mnew = fmaxf(mrun[n], rmax[n]);
          float sc = exp2f(mrun[n] - mnew);
          lsum[n] *= sc;             // lane-partial, sc lane-consistent per row
          mrun[n] = mnew;
#pragma unroll
          for (int e = 0; e < 4; ++e) {
            float bs = __shfl(sc, (lane & 48) + g * 4 + e);
#pragma unroll
            for (int hb = 0; hb < 4; ++hb) o[n][hb][e] *= bs;
          }
        }
      }

#pragma unroll
      for (int mp = 0; mp < 4; ++mp) {
        if (mp <= mpmax) {
#pragma unroll
          for (int n = 0; n < 2; ++n)
#pragma unroll
            for (int e = 0; e < 4; ++e) {
              float ev = exp2f(p[mp][n][e] - mrun[n]);
              p[mp][n][e] = ev;
              lsum[n] += ev;
            }
        }
      }

      // P -> bf16 A-fragments; PV from registers
      int kvhmax = mpmax >> 1;
#pragma unroll
      for (int kvh = 0; kvh < 2; ++kvh) {
        if (kvh > kvhmax) break;
        s16x8 pa[2];
#pragma unroll
        for (int n = 0; n < 2; ++n) {
          s16x8 tmp = {f2bf(p[2 * kvh][n][0]),     f2bf(p[2 * kvh][n][1]),
                       f2bf(p[2 * kvh][n][2]),     f2bf(p[2 * kvh][n][3]),
                       f2bf(p[2 * kvh + 1][n][0]), f2bf(p[2 * kvh + 1][n][1]),
                       f2bf(p[2 * kvh + 1][n][2]), f2bf(p[2 * kvh + 1][n][3])};
          pa[n] = tmp;
        }
#pragma unroll
        for (int hb = 0; hb < 4; ++hb)
#pragma unroll
          for (int n = 0; n < 2; ++n) o[n][hb] = MFMA16(pa[n], vf[kvh][hb], o[n][hb]);
      }
    };

    int tt = 0;
    for (; tt + 1 < ntw; tt += 2) {
      TILE(tt, kfA, kfB);
      TILE(tt + 1, kfB, kfA);
    }
    if (tt < ntw) TILE(tt, kfA, kfB);   // odd tail (prefetch guard tn<ntw holds)

    // epilogue: reduce l, O /= l, write [B,S,N*H] bf16
#pragma unroll
    for (int n = 0; n < 2; ++n) {
      float lt = lsum[n];
      lt += __shfl_xor(lt, 16);
      lt += __shfl_xor(lt, 32);
      float il = 1.0f / lt;
#pragma unroll
      for (int e = 0; e < 4; ++e) {
        float bv = __shfl(il, (lane & 48) + g * 4 + e);
        int s = qw + n * 16 + g * 4 + e;
#pragma unroll
        for (int hb = 0; hb < 4; ++hb) {
          int c = head * 64 + hb * 16 + r;
          Ob[(size_t)(batch * 2048 + s) * 1024 + c] = f2bf(o[n][hb][e] * bv);
        }
      }
    }
  }
}

// ---------- launch ----------
extern "C" void kernel_launch(void* const* d_in, const int* in_sizes, int n_in,
                              void* d_out, int out_size, void* d_ws, size_t ws_size,
                              hipStream_t stream) {
  const float* x    = (const float*)d_in[0];   // [4,2048,1024]
  const float* Wqkv = (const float*)d_in[1];   // [1024,3072]
  const float* bqkv = (const float*)d_in[2];   // [3072]
  const float* Wout = (const float*)d_in[3];   // [1024,1024]
  const float* bout = (const float*)d_in[4];   // [1024]
  float* out = (float*)d_out;

  char* ws = (char*)d_ws;
  short* Xb    = (short*)(ws);                          // 16 MB (reused as attn-out)
  short* Wqkvb = (short*)(ws + ((size_t)16 << 20));     // 6 MB
  short* Woutb = (short*)(ws + ((size_t)22 << 20));     // 2 MB
  short* Qb    = (short*)(ws + ((size_t)24 << 20));     // 16 MB
  short* Kb    = (short*)(ws + ((size_t)40 << 20));     // 16 MB
  short* Vb    = (short*)(ws + ((size_t)56 << 20));     // 16 MB (V^T per head)

  cvt_f32_bf16<<<2048, 256, 0, stream>>>(x, Xb, 4 * 2048 * 1024);
  cvt_f32_bf16<<<1024, 256, 0, stream>>>(Wqkv, Wqkvb, 1024 * 3072);
  cvt_f32_bf16<<<512, 256, 0, stream>>>(Wout, Woutb, 1024 * 1024);

  gemm_qkv<<<64 * 24, 256, 0, stream>>>(Xb, Wqkvb, bqkv, Qb, Kb, Vb);
  attn<<<2048, 64, 0, stream>>>(Qb, Kb, Vb, Xb);
  gemm_out<<<64 * 8, 256, 0, stream>>>(Xb, Woutb, bout, out);
}

// Round 9
// 294.524 us; speedup vs baseline: 1.2016x; 1.2016x over previous
//
#include <hip/hip_runtime.h>
#include <hip/hip_bf16.h>

// ---------- types ----------
typedef __attribute__((ext_vector_type(8))) short s16x8;   // 8 bf16 (4 VGPR)
typedef __attribute__((ext_vector_type(4))) short s16x4;   // 4 bf16
typedef __attribute__((ext_vector_type(4))) float f32x4;

#define MFMA16(a, b, c) __builtin_amdgcn_mfma_f32_16x16x32_bf16(a, b, c, 0, 0, 0)

__device__ __forceinline__ short f2bf(float f) {
  unsigned int x = __builtin_bit_cast(unsigned int, f);
  x += 0x7fffu + ((x >> 16) & 1u);   // RNE; inputs always finite here
  return (short)(x >> 16);
}

// fragment permutation within a 32-block: element with true index k stored at
// c(k) = g*8 + b*4 + j for k = b*16 + g*4 + j  -> lane (r,g)'s 8 frag elems
// {4g+j, 16+4g+j} are contiguous at offset g*8 -> single b128 load.
__device__ __forceinline__ int cperm(int k) {
  return ((k & 12) << 1) | ((k >> 4) << 2) | (k & 3);
}

#define LDT 40   // padded LDS row length for GEMM tiles

// ---------- fp32 -> bf16 convert ----------
__global__ void cvt_f32_bf16(const float* __restrict__ in, short* __restrict__ out, int n) {
  int idx = blockIdx.x * blockDim.x + threadIdx.x;
  int stride = gridDim.x * blockDim.x;
  for (int i = idx * 4; i < n; i += stride * 4) {
    float4 v = *(const float4*)(in + i);
    s16x4 o;
    o[0] = f2bf(v.x); o[1] = f2bf(v.y); o[2] = f2bf(v.z); o[3] = f2bf(v.w);
    *(s16x4*)(out + i) = o;
  }
}

// ---------- GEMM1: qkv = Xb @ Wqkv + b ----------
// Q: [bn][s][h-cperm], pre-scaled by 0.125*log2(e) (exp2-domain softmax)
// K: [bn][s][h-cperm]
// V: [bn][h][s-cperm]  (transposed per head, kv-dim cperm'd)
__global__ __launch_bounds__(256) void gemm_qkv(
    const short* __restrict__ X, const short* __restrict__ W,
    const float* __restrict__ bias,
    short* __restrict__ Qo, short* __restrict__ Ko, short* __restrict__ Vo) {
  const int N = 3072, Kd = 1024;
  __shared__ short As[128 * LDT];
  __shared__ short Bs[128 * LDT];
  int t = threadIdx.x;
  int nTN = N / 128;
  int m0 = (blockIdx.x / nTN) * 128;
  int n0 = (blockIdx.x % nTN) * 128;
  int lane = t & 63, w = t >> 6;
  int wr = (w >> 1) * 64, wc = (w & 1) * 64;
  int r = lane & 15, g = lane >> 4;

  int ar = t >> 1;
  int ak = (t & 1) << 4;
  int bk = t & 31;
  int bc = (t >> 5) << 4;
  int cbk = cperm(bk);

  f32x4 acc[4][4];
  const f32x4 z4 = {0.f, 0.f, 0.f, 0.f};
#pragma unroll
  for (int i = 0; i < 4; ++i)
#pragma unroll
    for (int j = 0; j < 4; ++j) acc[i][j] = z4;

  for (int kt = 0; kt < Kd; kt += 32) {
    if (kt) __syncthreads();
    const short* xr = X + (size_t)(m0 + ar) * Kd + kt + ak;
    s16x8 va0 = *(const s16x8*)(xr);
    s16x8 va1 = *(const s16x8*)(xr + 8);
    short* Ad = &As[ar * LDT];
    *(s16x4*)(Ad + cperm(ak))      = __builtin_shufflevector(va0, va0, 0, 1, 2, 3);
    *(s16x4*)(Ad + cperm(ak + 4))  = __builtin_shufflevector(va0, va0, 4, 5, 6, 7);
    *(s16x4*)(Ad + cperm(ak + 8))  = __builtin_shufflevector(va1, va1, 0, 1, 2, 3);
    *(s16x4*)(Ad + cperm(ak + 12)) = __builtin_shufflevector(va1, va1, 4, 5, 6, 7);
    const short* wrp = W + (size_t)(kt + bk) * N + n0 + bc;
    s16x8 vb0 = *(const s16x8*)(wrp);
    s16x8 vb1 = *(const s16x8*)(wrp + 8);
#pragma unroll
    for (int i = 0; i < 8; ++i) Bs[(bc + i) * LDT + cbk] = vb0[i];
#pragma unroll
    for (int i = 0; i < 8; ++i) Bs[(bc + 8 + i) * LDT + cbk] = vb1[i];
    __syncthreads();

    s16x8 af[4], bfr[4];
#pragma unroll
    for (int mi = 0; mi < 4; ++mi)
      af[mi] = *(const s16x8*)(&As[(wr + mi * 16 + r) * LDT + g * 8]);
#pragma unroll
    for (int ni = 0; ni < 4; ++ni)
      bfr[ni] = *(const s16x8*)(&Bs[(wc + ni * 16 + r) * LDT + g * 8]);
#pragma unroll
    for (int mi = 0; mi < 4; ++mi)
#pragma unroll
      for (int ni = 0; ni < 4; ++ni)
        acc[mi][ni] = MFMA16(af[mi], bfr[ni], acc[mi][ni]);
  }

#pragma unroll
  for (int ni = 0; ni < 4; ++ni) {
    int col = n0 + wc + ni * 16 + r;
    float bv = bias[col];
    int which = col >> 10;
    int rem = col & 1023;
    int head = rem >> 6, h = rem & 63;
    short* dst = (which == 0) ? Qo : (which == 1) ? Ko : Vo;
    float qsc = (which == 0) ? 0.125f * 1.44269504f : 1.0f;
    int hp = (h & 32) | cperm(h & 31);   // h-dim cperm for Q/K
#pragma unroll
    for (int mi = 0; mi < 4; ++mi)
#pragma unroll
      for (int e = 0; e < 4; ++e) {
        int row = m0 + wr + mi * 16 + g * 4 + e;
        int b = row >> 11, s = row & 2047;
        size_t idx;
        if (which == 2)
          idx = ((size_t)(b * 16 + head) * 64 + h) * 2048 + ((s & ~31) | cperm(s & 31));
        else
          idx = ((size_t)(b * 16 + head) * 2048 + s) * 64 + hp;
        dst[idx] = f2bf((acc[mi][ni][e] + bv) * qsc);
      }
  }
}

// ---------- GEMM2: out = AttnOut @ Wout + b, fp32 out ----------
__global__ __launch_bounds__(256) void gemm_out(
    const short* __restrict__ X, const short* __restrict__ W,
    const float* __restrict__ bias, float* __restrict__ Out) {
  const int N = 1024, Kd = 1024;
  __shared__ short As[128 * LDT];
  __shared__ short Bs[128 * LDT];
  int t = threadIdx.x;
  int nTN = N / 128;
  int m0 = (blockIdx.x / nTN) * 128;
  int n0 = (blockIdx.x % nTN) * 128;
  int lane = t & 63, w = t >> 6;
  int wr = (w >> 1) * 64, wc = (w & 1) * 64;
  int r = lane & 15, g = lane >> 4;
  int ar = t >> 1, ak = (t & 1) << 4;
  int bk = t & 31, bc = (t >> 5) << 4;
  int cbk = cperm(bk);

  f32x4 acc[4][4];
  const f32x4 z4 = {0.f, 0.f, 0.f, 0.f};
#pragma unroll
  for (int i = 0; i < 4; ++i)
#pragma unroll
    for (int j = 0; j < 4; ++j) acc[i][j] = z4;

  for (int kt = 0; kt < Kd; kt += 32) {
    if (kt) __syncthreads();
    const short* xr = X + (size_t)(m0 + ar) * Kd + kt + ak;
    s16x8 va0 = *(const s16x8*)(xr);
    s16x8 va1 = *(const s16x8*)(xr + 8);
    short* Ad = &As[ar * LDT];
    *(s16x4*)(Ad + cperm(ak))      = __builtin_shufflevector(va0, va0, 0, 1, 2, 3);
    *(s16x4*)(Ad + cperm(ak + 4))  = __builtin_shufflevector(va0, va0, 4, 5, 6, 7);
    *(s16x4*)(Ad + cperm(ak + 8))  = __builtin_shufflevector(va1, va1, 0, 1, 2, 3);
    *(s16x4*)(Ad + cperm(ak + 12)) = __builtin_shufflevector(va1, va1, 4, 5, 6, 7);
    const short* wrp = W + (size_t)(kt + bk) * N + n0 + bc;
    s16x8 vb0 = *(const s16x8*)(wrp);
    s16x8 vb1 = *(const s16x8*)(wrp + 8);
#pragma unroll
    for (int i = 0; i < 8; ++i) Bs[(bc + i) * LDT + cbk] = vb0[i];
#pragma unroll
    for (int i = 0; i < 8; ++i) Bs[(bc + 8 + i) * LDT + cbk] = vb1[i];
    __syncthreads();

    s16x8 af[4], bfr[4];
#pragma unroll
    for (int mi = 0; mi < 4; ++mi)
      af[mi] = *(const s16x8*)(&As[(wr + mi * 16 + r) * LDT + g * 8]);
#pragma unroll
    for (int ni = 0; ni < 4; ++ni)
      bfr[ni] = *(const s16x8*)(&Bs[(wc + ni * 16 + r) * LDT + g * 8]);
#pragma unroll
    for (int mi = 0; mi < 4; ++mi)
#pragma unroll
      for (int ni = 0; ni < 4; ++ni)
        acc[mi][ni] = MFMA16(af[mi], bfr[ni], acc[mi][ni]);
  }

#pragma unroll
  for (int ni = 0; ni < 4; ++ni) {
    int col = n0 + wc + ni * 16 + r;
    float bv = bias[col];
#pragma unroll
    for (int mi = 0; mi < 4; ++mi)
#pragma unroll
      for (int e = 0; e < 4; ++e) {
        int row = m0 + wr + mi * 16 + g * 4 + e;
        Out[(size_t)row * N + col] = acc[mi][ni][e] + bv;
      }
  }
}

// ---------- causal flash attention ----------
// 512 blocks x 4 waves. Block (bn, p): wave w runs strip (qt=15-p, w) then
// (qt=p, 3-w) -> EVERY wave = 33 units, EVERY block = 33 units (no tail), and
// the 4 waves of a block scan the SAME head's kv tiles in near-lockstep
// (L1-shared K/V). XCD swizzle: blockIdx = (bn&7) + 8*(bn>>3) + 64*p puts all
// 8 blocks of head bn on XCD bn&7 -> per-XCD K/V working set = 4MB = L2.
// All-register, barrier-free; K dbuf 1 tile ahead; V issued at tile top.
__global__ __launch_bounds__(256) void attn(
    const short* __restrict__ Qb, const short* __restrict__ Kb,
    const short* __restrict__ Vt, short* __restrict__ Ob) {
  const int S = 2048, H = 64;
  int i = blockIdx.x;                // 0..511 (swizzled)
  int bn = ((i >> 3) & 7) * 8 + (i & 7);
  int p  = i >> 6;                   // 0..7
  int batch = bn >> 4, head = bn & 15;
  int lane = threadIdx.x & 63, w = threadIdx.x >> 6;
  int r = lane & 15, g = lane >> 4;

  const short* Qh = Qb + (size_t)bn * S * H;
  const short* Kh = Kb + (size_t)bn * S * H;
  const short* Vh = Vt + (size_t)bn * S * H;   // [h][s-cperm]
  const f32x4 z4 = {0.f, 0.f, 0.f, 0.f};

  for (int sp = 0; sp < 2; ++sp) {
    int qt = sp ? p : (15 - p);
    int wv = sp ? (3 - w) : w;
    int qw = qt * 128 + wv * 32;
    int ntw = ((qw + 31) >> 6) + 1;  // per-strip kv-tile count

    // Q fragments (B-operand [k=h][col=q]); single b128 each
    s16x8 qf[2][2];
#pragma unroll
    for (int n = 0; n < 2; ++n)
#pragma unroll
      for (int ks = 0; ks < 2; ++ks)
        qf[n][ks] = *(const s16x8*)(Qh + (size_t)(qw + n * 16 + r) * H + ks * 32 + g * 8);

    f32x4 o[2][4];
#pragma unroll
    for (int n = 0; n < 2; ++n)
#pragma unroll
      for (int hb = 0; hb < 4; ++hb) o[n][hb] = z4;
    float mrun[2] = {-__builtin_inff(), -__builtin_inff()};
    float lsum[2] = {0.f, 0.f};

    auto LOADK = [&](int kv0, s16x8 (&kf)[4][2]) {
#pragma unroll
      for (int mp = 0; mp < 4; ++mp)
#pragma unroll
        for (int ks = 0; ks < 2; ++ks)
          kf[mp][ks] = *(const s16x8*)(Kh + (size_t)(kv0 + mp * 16 + r) * H + ks * 32 + g * 8);
    };

    s16x8 kfA[4][2], kfB[4][2];
    LOADK(0, kfA);

    auto TILE = [&](int tt, s16x8 (&kfc)[4][2], s16x8 (&kfn)[4][2]) {
      int kv0 = tt * 64;
      bool need_mask = (kv0 + 63 > qw);
      int mpmax = (qw + 31 - kv0) >> 4; if (mpmax > 3) mpmax = 3;

      // V^T fragments (B-op for PV): issue first, consumed after softmax
      s16x8 vf[2][4];
#pragma unroll
      for (int kvh = 0; kvh < 2; ++kvh)
#pragma unroll
        for (int hb = 0; hb < 4; ++hb)
          vf[kvh][hb] = *(const s16x8*)(Vh + (size_t)(hb * 16 + r) * S + kv0 + kvh * 32 + g * 8);

      // prefetch K(tt+1) — consumed next tile
      int tn = tt + 1;
      if (tn < ntw) LOADK(tn * 64, kfn);

      float p_[4][2][4];
      float rmax[2] = {-__builtin_inff(), -__builtin_inff()};
#pragma unroll
      for (int mp = 0; mp < 4; ++mp) {
        if (mp <= mpmax) {
          f32x4 st[2] = {z4, z4};
#pragma unroll
          for (int n = 0; n < 2; ++n)
#pragma unroll
            for (int ks = 0; ks < 2; ++ks)
              st[n] = MFMA16(kfc[mp][ks], qf[n][ks], st[n]);
#pragma unroll
          for (int n = 0; n < 2; ++n)
#pragma unroll
            for (int e = 0; e < 4; ++e) {
              float v = st[n][e];    // exp2-domain (scaled via Q)
              if (need_mask) {
                int kv = kv0 + mp * 16 + g * 4 + e;
                int q = qw + n * 16 + r;
                if (kv > q) v = -__builtin_inff();
              }
              p_[mp][n][e] = v;
              rmax[n] = fmaxf(rmax[n], v);
            }
        } else {
#pragma unroll
          for (int n = 0; n < 2; ++n)
#pragma unroll
            for (int e = 0; e < 4; ++e) p_[mp][n][e] = 0.f;
        }
      }

#pragma unroll
      for (int n = 0; n < 2; ++n) {
        rmax[n] = fmaxf(rmax[n], __shfl_xor(rmax[n], 16));
        rmax[n] = fmaxf(rmax[n], __shfl_xor(rmax[n], 32));
      }

      // defer-rescale (THR=8 in log2 domain)
#pragma unroll
      for (int n = 0; n < 2; ++n) {
        if (!__all(rmax[n] - mrun[n] <= 8.0f)) {
          float mnew = fmaxf(mrun[n], rmax[n]);
          float sc = exp2f(mrun[n] - mnew);
          lsum[n] *= sc;             // lane-partial, sc lane-consistent per row
          mrun[n] = mnew;
#pragma unroll
          for (int e = 0; e < 4; ++e) {
            float bs = __shfl(sc, (lane & 48) + g * 4 + e);
#pragma unroll
            for (int hb = 0; hb < 4; ++hb) o[n][hb][e] *= bs;
          }
        }
      }

#pragma unroll
      for (int mp = 0; mp < 4; ++mp) {
        if (mp <= mpmax) {
#pragma unroll
          for (int n = 0; n < 2; ++n)
#pragma unroll
            for (int e = 0; e < 4; ++e) {
              float ev = exp2f(p_[mp][n][e] - mrun[n]);
              p_[mp][n][e] = ev;
              lsum[n] += ev;
            }
        }
      }

      // P -> bf16 A-fragments; PV from registers
      int kvhmax = mpmax >> 1;
#pragma unroll
      for (int kvh = 0; kvh < 2; ++kvh) {
        if (kvh > kvhmax) break;
        s16x8 pa[2];
#pragma unroll
        for (int n = 0; n < 2; ++n) {
          s16x8 tmp = {f2bf(p_[2 * kvh][n][0]),     f2bf(p_[2 * kvh][n][1]),
                       f2bf(p_[2 * kvh][n][2]),     f2bf(p_[2 * kvh][n][3]),
                       f2bf(p_[2 * kvh + 1][n][0]), f2bf(p_[2 * kvh + 1][n][1]),
                       f2bf(p_[2 * kvh + 1][n][2]), f2bf(p_[2 * kvh + 1][n][3])};
          pa[n] = tmp;
        }
#pragma unroll
        for (int hb = 0; hb < 4; ++hb)
#pragma unroll
          for (int n = 0; n < 2; ++n) o[n][hb] = MFMA16(pa[n], vf[kvh][hb], o[n][hb]);
      }
    };

    int tt = 0;
    for (; tt + 1 < ntw; tt += 2) {
      TILE(tt, kfA, kfB);
      TILE(tt + 1, kfB, kfA);
    }
    if (tt < ntw) TILE(tt, kfA, kfB);   // odd tail

    // epilogue: reduce l, O /= l, write [B,S,N*H] bf16
#pragma unroll
    for (int n = 0; n < 2; ++n) {
      float lt = lsum[n];
      lt += __shfl_xor(lt, 16);
      lt += __shfl_xor(lt, 32);
      float il = 1.0f / lt;
#pragma unroll
      for (int e = 0; e < 4; ++e) {
        float bv = __shfl(il, (lane & 48) + g * 4 + e);
        int s = qw + n * 16 + g * 4 + e;
#pragma unroll
        for (int hb = 0; hb < 4; ++hb) {
          int c = head * 64 + hb * 16 + r;
          Ob[(size_t)(batch * 2048 + s) * 1024 + c] = f2bf(o[n][hb][e] * bv);
        }
      }
    }
  }
}

// ---------- launch ----------
extern "C" void kernel_launch(void* const* d_in, const int* in_sizes, int n_in,
                              void* d_out, int out_size, void* d_ws, size_t ws_size,
                              hipStream_t stream) {
  const float* x    = (const float*)d_in[0];   // [4,2048,1024]
  const float* Wqkv = (const float*)d_in[1];   // [1024,3072]
  const float* bqkv = (const float*)d_in[2];   // [3072]
  const float* Wout = (const float*)d_in[3];   // [1024,1024]
  const float* bout = (const float*)d_in[4];   // [1024]
  float* out = (float*)d_out;

  char* ws = (char*)d_ws;
  short* Xb    = (short*)(ws);                          // 16 MB (reused as attn-out)
  short* Wqkvb = (short*)(ws + ((size_t)16 << 20));     // 6 MB
  short* Woutb = (short*)(ws + ((size_t)22 << 20));     // 2 MB
  short* Qb    = (short*)(ws + ((size_t)24 << 20));     // 16 MB
  short* Kb    = (short*)(ws + ((size_t)40 << 20));     // 16 MB
  short* Vb    = (short*)(ws + ((size_t)56 << 20));     // 16 MB (V^T per head)

  cvt_f32_bf16<<<2048, 256, 0, stream>>>(x, Xb, 4 * 2048 * 1024);
  cvt_f32_bf16<<<1024, 256, 0, stream>>>(Wqkv, Wqkvb, 1024 * 3072);
  cvt_f32_bf16<<<512, 256, 0, stream>>>(Wout, Woutb, 1024 * 1024);

  gemm_qkv<<<64 * 24, 256, 0, stream>>>(Xb, Wqkvb, bqkv, Qb, Kb, Vb);
  attn<<<512, 256, 0, stream>>>(Qb, Kb, Vb, Xb);
  gemm_out<<<64 * 8, 256, 0, stream>>>(Xb, Woutb, bout, out);
}

// Round 10
// 284.685 us; speedup vs baseline: 1.2431x; 1.0346x over previous
//
#include <hip/hip_runtime.h>
#include <hip/hip_bf16.h>

// ---------- types ----------
typedef __attribute__((ext_vector_type(8))) short s16x8;   // 8 bf16 (4 VGPR)
typedef __attribute__((ext_vector_type(4))) short s16x4;   // 4 bf16
typedef __attribute__((ext_vector_type(4))) float f32x4;

#define MFMA16(a, b, c) __builtin_amdgcn_mfma_f32_16x16x32_bf16(a, b, c, 0, 0, 0)
#define EXP2(x) __builtin_amdgcn_exp2f(x)   // raw v_exp_f32 (libm exp2f is a ~15-op OCML sequence)

__device__ __forceinline__ short f2bf(float f) {
  unsigned int x = __builtin_bit_cast(unsigned int, f);
  x += 0x7fffu + ((x >> 16) & 1u);   // RNE; inputs always finite here
  return (short)(x >> 16);
}

// fragment permutation within a 32-block: element with true index k stored at
// c(k) = g*8 + b*4 + j for k = b*16 + g*4 + j  -> lane (r,g)'s 8 frag elems
// {4g+j, 16+4g+j} are contiguous at offset g*8 -> single b128 load.
__device__ __forceinline__ int cperm(int k) {
  return ((k & 12) << 1) | ((k >> 4) << 2) | (k & 3);
}

#define LDT 40   // padded LDS row length for GEMM tiles

// ---------- fp32 -> bf16 convert ----------
__global__ void cvt_f32_bf16(const float* __restrict__ in, short* __restrict__ out, int n) {
  int idx = blockIdx.x * blockDim.x + threadIdx.x;
  int stride = gridDim.x * blockDim.x;
  for (int i = idx * 4; i < n; i += stride * 4) {
    float4 v = *(const float4*)(in + i);
    s16x4 o;
    o[0] = f2bf(v.x); o[1] = f2bf(v.y); o[2] = f2bf(v.z); o[3] = f2bf(v.w);
    *(s16x4*)(out + i) = o;
  }
}

// ---------- GEMM1: qkv = Xb @ Wqkv + b ----------
// Q: [bn][s][h-cperm], pre-scaled by 0.125*log2(e) (exp2-domain softmax)
// K: [bn][s][h-cperm]
// V: [bn][h][s-cperm]  (transposed per head, kv-dim cperm'd)
__global__ __launch_bounds__(256) void gemm_qkv(
    const short* __restrict__ X, const short* __restrict__ W,
    const float* __restrict__ bias,
    short* __restrict__ Qo, short* __restrict__ Ko, short* __restrict__ Vo) {
  const int N = 3072, Kd = 1024;
  __shared__ short As[128 * LDT];
  __shared__ short Bs[128 * LDT];
  int t = threadIdx.x;
  int nTN = N / 128;
  int m0 = (blockIdx.x / nTN) * 128;
  int n0 = (blockIdx.x % nTN) * 128;
  int lane = t & 63, w = t >> 6;
  int wr = (w >> 1) * 64, wc = (w & 1) * 64;
  int r = lane & 15, g = lane >> 4;

  int ar = t >> 1;
  int ak = (t & 1) << 4;
  int bk = t & 31;
  int bc = (t >> 5) << 4;
  int cbk = cperm(bk);

  f32x4 acc[4][4];
  const f32x4 z4 = {0.f, 0.f, 0.f, 0.f};
#pragma unroll
  for (int i = 0; i < 4; ++i)
#pragma unroll
    for (int j = 0; j < 4; ++j) acc[i][j] = z4;

  for (int kt = 0; kt < Kd; kt += 32) {
    if (kt) __syncthreads();
    const short* xr = X + (size_t)(m0 + ar) * Kd + kt + ak;
    s16x8 va0 = *(const s16x8*)(xr);
    s16x8 va1 = *(const s16x8*)(xr + 8);
    short* Ad = &As[ar * LDT];
    *(s16x4*)(Ad + cperm(ak))      = __builtin_shufflevector(va0, va0, 0, 1, 2, 3);
    *(s16x4*)(Ad + cperm(ak + 4))  = __builtin_shufflevector(va0, va0, 4, 5, 6, 7);
    *(s16x4*)(Ad + cperm(ak + 8))  = __builtin_shufflevector(va1, va1, 0, 1, 2, 3);
    *(s16x4*)(Ad + cperm(ak + 12)) = __builtin_shufflevector(va1, va1, 4, 5, 6, 7);
    const short* wrp = W + (size_t)(kt + bk) * N + n0 + bc;
    s16x8 vb0 = *(const s16x8*)(wrp);
    s16x8 vb1 = *(const s16x8*)(wrp + 8);
#pragma unroll
    for (int i = 0; i < 8; ++i) Bs[(bc + i) * LDT + cbk] = vb0[i];
#pragma unroll
    for (int i = 0; i < 8; ++i) Bs[(bc + 8 + i) * LDT + cbk] = vb1[i];
    __syncthreads();

    s16x8 af[4], bfr[4];
#pragma unroll
    for (int mi = 0; mi < 4; ++mi)
      af[mi] = *(const s16x8*)(&As[(wr + mi * 16 + r) * LDT + g * 8]);
#pragma unroll
    for (int ni = 0; ni < 4; ++ni)
      bfr[ni] = *(const s16x8*)(&Bs[(wc + ni * 16 + r) * LDT + g * 8]);
#pragma unroll
    for (int mi = 0; mi < 4; ++mi)
#pragma unroll
      for (int ni = 0; ni < 4; ++ni)
        acc[mi][ni] = MFMA16(af[mi], bfr[ni], acc[mi][ni]);
  }

#pragma unroll
  for (int ni = 0; ni < 4; ++ni) {
    int col = n0 + wc + ni * 16 + r;
    float bv = bias[col];
    int which = col >> 10;
    int rem = col & 1023;
    int head = rem >> 6, h = rem & 63;
    short* dst = (which == 0) ? Qo : (which == 1) ? Ko : Vo;
    float qsc = (which == 0) ? 0.125f * 1.44269504f : 1.0f;
    int hp = (h & 32) | cperm(h & 31);   // h-dim cperm for Q/K
#pragma unroll
    for (int mi = 0; mi < 4; ++mi)
#pragma unroll
      for (int e = 0; e < 4; ++e) {
        int row = m0 + wr + mi * 16 + g * 4 + e;
        int b = row >> 11, s = row & 2047;
        size_t idx;
        if (which == 2)
          idx = ((size_t)(b * 16 + head) * 64 + h) * 2048 + ((s & ~31) | cperm(s & 31));
        else
          idx = ((size_t)(b * 16 + head) * 2048 + s) * 64 + hp;
        dst[idx] = f2bf((acc[mi][ni][e] + bv) * qsc);
      }
  }
}

// ---------- GEMM2: out = AttnOut @ Wout + b, fp32 out ----------
__global__ __launch_bounds__(256) void gemm_out(
    const short* __restrict__ X, const short* __restrict__ W,
    const float* __restrict__ bias, float* __restrict__ Out) {
  const int N = 1024, Kd = 1024;
  __shared__ short As[128 * LDT];
  __shared__ short Bs[128 * LDT];
  int t = threadIdx.x;
  int nTN = N / 128;
  int m0 = (blockIdx.x / nTN) * 128;
  int n0 = (blockIdx.x % nTN) * 128;
  int lane = t & 63, w = t >> 6;
  int wr = (w >> 1) * 64, wc = (w & 1) * 64;
  int r = lane & 15, g = lane >> 4;
  int ar = t >> 1, ak = (t & 1) << 4;
  int bk = t & 31, bc = (t >> 5) << 4;
  int cbk = cperm(bk);

  f32x4 acc[4][4];
  const f32x4 z4 = {0.f, 0.f, 0.f, 0.f};
#pragma unroll
  for (int i = 0; i < 4; ++i)
#pragma unroll
    for (int j = 0; j < 4; ++j) acc[i][j] = z4;

  for (int kt = 0; kt < Kd; kt += 32) {
    if (kt) __syncthreads();
    const short* xr = X + (size_t)(m0 + ar) * Kd + kt + ak;
    s16x8 va0 = *(const s16x8*)(xr);
    s16x8 va1 = *(const s16x8*)(xr + 8);
    short* Ad = &As[ar * LDT];
    *(s16x4*)(Ad + cperm(ak))      = __builtin_shufflevector(va0, va0, 0, 1, 2, 3);
    *(s16x4*)(Ad + cperm(ak + 4))  = __builtin_shufflevector(va0, va0, 4, 5, 6, 7);
    *(s16x4*)(Ad + cperm(ak + 8))  = __builtin_shufflevector(va1, va1, 0, 1, 2, 3);
    *(s16x4*)(Ad + cperm(ak + 12)) = __builtin_shufflevector(va1, va1, 4, 5, 6, 7);
    const short* wrp = W + (size_t)(kt + bk) * N + n0 + bc;
    s16x8 vb0 = *(const s16x8*)(wrp);
    s16x8 vb1 = *(const s16x8*)(wrp + 8);
#pragma unroll
    for (int i = 0; i < 8; ++i) Bs[(bc + i) * LDT + cbk] = vb0[i];
#pragma unroll
    for (int i = 0; i < 8; ++i) Bs[(bc + 8 + i) * LDT + cbk] = vb1[i];
    __syncthreads();

    s16x8 af[4], bfr[4];
#pragma unroll
    for (int mi = 0; mi < 4; ++mi)
      af[mi] = *(const s16x8*)(&As[(wr + mi * 16 + r) * LDT + g * 8]);
#pragma unroll
    for (int ni = 0; ni < 4; ++ni)
      bfr[ni] = *(const s16x8*)(&Bs[(wc + ni * 16 + r) * LDT + g * 8]);
#pragma unroll
    for (int mi = 0; mi < 4; ++mi)
#pragma unroll
      for (int ni = 0; ni < 4; ++ni)
        acc[mi][ni] = MFMA16(af[mi], bfr[ni], acc[mi][ni]);
  }

#pragma unroll
  for (int ni = 0; ni < 4; ++ni) {
    int col = n0 + wc + ni * 16 + r;
    float bv = bias[col];
#pragma unroll
    for (int mi = 0; mi < 4; ++mi)
#pragma unroll
      for (int e = 0; e < 4; ++e) {
        int row = m0 + wr + mi * 16 + g * 4 + e;
        Out[(size_t)row * N + col] = acc[mi][ni][e] + bv;
      }
  }
}

// ---------- causal flash attention ----------
// 512 blocks x 4 waves. Block (bn, p): wave w runs strip (qt=15-p, w) then
// (qt=p, 3-w) -> EVERY wave = 33 units (no tail); 4 waves of a block scan the
// SAME head's kv tiles near-lockstep (L1/L2-shared). XCD swizzle keeps all 8
// blocks of a head on one XCD. All-register, barrier-free; K dbuf; V at tile
// top. This round: exp2f -> __builtin_amdgcn_exp2f (single v_exp_f32).
__global__ __launch_bounds__(256) void attn(
    const short* __restrict__ Qb, const short* __restrict__ Kb,
    const short* __restrict__ Vt, short* __restrict__ Ob) {
  const int S = 2048, H = 64;
  int i = blockIdx.x;                // 0..511 (swizzled)
  int bn = ((i >> 3) & 7) * 8 + (i & 7);
  int p  = i >> 6;                   // 0..7
  int batch = bn >> 4, head = bn & 15;
  int lane = threadIdx.x & 63, w = threadIdx.x >> 6;
  int r = lane & 15, g = lane >> 4;

  const short* Qh = Qb + (size_t)bn * S * H;
  const short* Kh = Kb + (size_t)bn * S * H;
  const short* Vh = Vt + (size_t)bn * S * H;   // [h][s-cperm]
  const f32x4 z4 = {0.f, 0.f, 0.f, 0.f};

  for (int sp = 0; sp < 2; ++sp) {
    int qt = sp ? p : (15 - p);
    int wv = sp ? (3 - w) : w;
    int qw = qt * 128 + wv * 32;
    int ntw = ((qw + 31) >> 6) + 1;  // per-strip kv-tile count

    // Q fragments (B-operand [k=h][col=q]); single b128 each
    s16x8 qf[2][2];
#pragma unroll
    for (int n = 0; n < 2; ++n)
#pragma unroll
      for (int ks = 0; ks < 2; ++ks)
        qf[n][ks] = *(const s16x8*)(Qh + (size_t)(qw + n * 16 + r) * H + ks * 32 + g * 8);

    f32x4 o[2][4];
#pragma unroll
    for (int n = 0; n < 2; ++n)
#pragma unroll
      for (int hb = 0; hb < 4; ++hb) o[n][hb] = z4;
    float mrun[2] = {-__builtin_inff(), -__builtin_inff()};
    float lsum[2] = {0.f, 0.f};

    auto LOADK = [&](int kv0, s16x8 (&kf)[4][2]) {
#pragma unroll
      for (int mp = 0; mp < 4; ++mp)
#pragma unroll
        for (int ks = 0; ks < 2; ++ks)
          kf[mp][ks] = *(const s16x8*)(Kh + (size_t)(kv0 + mp * 16 + r) * H + ks * 32 + g * 8);
    };

    s16x8 kfA[4][2], kfB[4][2];
    LOADK(0, kfA);

    auto TILE = [&](int tt, s16x8 (&kfc)[4][2], s16x8 (&kfn)[4][2]) {
      int kv0 = tt * 64;
      bool need_mask = (kv0 + 63 > qw);
      int mpmax = (qw + 31 - kv0) >> 4; if (mpmax > 3) mpmax = 3;

      // V^T fragments (B-op for PV): issue first, consumed after softmax
      s16x8 vf[2][4];
#pragma unroll
      for (int kvh = 0; kvh < 2; ++kvh)
#pragma unroll
        for (int hb = 0; hb < 4; ++hb)
          vf[kvh][hb] = *(const s16x8*)(Vh + (size_t)(hb * 16 + r) * S + kv0 + kvh * 32 + g * 8);

      // prefetch K(tt+1) — consumed next tile
      int tn = tt + 1;
      if (tn < ntw) LOADK(tn * 64, kfn);

      float p_[4][2][4];
      float rmax[2] = {-__builtin_inff(), -__builtin_inff()};
#pragma unroll
      for (int mp = 0; mp < 4; ++mp) {
        if (mp <= mpmax) {
          f32x4 st[2] = {z4, z4};
#pragma unroll
          for (int n = 0; n < 2; ++n)
#pragma unroll
            for (int ks = 0; ks < 2; ++ks)
              st[n] = MFMA16(kfc[mp][ks], qf[n][ks], st[n]);
#pragma unroll
          for (int n = 0; n < 2; ++n)
#pragma unroll
            for (int e = 0; e < 4; ++e) {
              float v = st[n][e];    // exp2-domain (scaled via Q)
              if (need_mask) {
                int kv = kv0 + mp * 16 + g * 4 + e;
                int q = qw + n * 16 + r;
                if (kv > q) v = -__builtin_inff();
              }
              p_[mp][n][e] = v;
              rmax[n] = fmaxf(rmax[n], v);
            }
        } else {
#pragma unroll
          for (int n = 0; n < 2; ++n)
#pragma unroll
            for (int e = 0; e < 4; ++e) p_[mp][n][e] = 0.f;
        }
      }

#pragma unroll
      for (int n = 0; n < 2; ++n) {
        rmax[n] = fmaxf(rmax[n], __shfl_xor(rmax[n], 16));
        rmax[n] = fmaxf(rmax[n], __shfl_xor(rmax[n], 32));
      }

      // defer-rescale (THR=8 in log2 domain)
#pragma unroll
      for (int n = 0; n < 2; ++n) {
        if (!__all(rmax[n] - mrun[n] <= 8.0f)) {
          float mnew = fmaxf(mrun[n], rmax[n]);
          float sc = EXP2(mrun[n] - mnew);
          lsum[n] *= sc;             // lane-partial, sc lane-consistent per row
          mrun[n] = mnew;
#pragma unroll
          for (int e = 0; e < 4; ++e) {
            float bs = __shfl(sc, (lane & 48) + g * 4 + e);
#pragma unroll
            for (int hb = 0; hb < 4; ++hb) o[n][hb][e] *= bs;
          }
        }
      }

#pragma unroll
      for (int mp = 0; mp < 4; ++mp) {
        if (mp <= mpmax) {
#pragma unroll
          for (int n = 0; n < 2; ++n)
#pragma unroll
            for (int e = 0; e < 4; ++e) {
              float ev = EXP2(p_[mp][n][e] - mrun[n]);
              p_[mp][n][e] = ev;
              lsum[n] += ev;
            }
        }
      }

      // P -> bf16 A-fragments; PV from registers
      int kvhmax = mpmax >> 1;
#pragma unroll
      for (int kvh = 0; kvh < 2; ++kvh) {
        if (kvh > kvhmax) break;
        s16x8 pa[2];
#pragma unroll
        for (int n = 0; n < 2; ++n) {
          s16x8 tmp = {f2bf(p_[2 * kvh][n][0]),     f2bf(p_[2 * kvh][n][1]),
                       f2bf(p_[2 * kvh][n][2]),     f2bf(p_[2 * kvh][n][3]),
                       f2bf(p_[2 * kvh + 1][n][0]), f2bf(p_[2 * kvh + 1][n][1]),
                       f2bf(p_[2 * kvh + 1][n][2]), f2bf(p_[2 * kvh + 1][n][3])};
          pa[n] = tmp;
        }
#pragma unroll
        for (int hb = 0; hb < 4; ++hb)
#pragma unroll
          for (int n = 0; n < 2; ++n) o[n][hb] = MFMA16(pa[n], vf[kvh][hb], o[n][hb]);
      }
    };

    int tt = 0;
    for (; tt + 1 < ntw; tt += 2) {
      TILE(tt, kfA, kfB);
      TILE(tt + 1, kfB, kfA);
    }
    if (tt < ntw) TILE(tt, kfA, kfB);   // odd tail

    // epilogue: reduce l, O /= l, write [B,S,N*H] bf16
#pragma unroll
    for (int n = 0; n < 2; ++n) {
      float lt = lsum[n];
      lt += __shfl_xor(lt, 16);
      lt += __shfl_xor(lt, 32);
      float il = 1.0f / lt;
#pragma unroll
      for (int e = 0; e < 4; ++e) {
        float bv = __shfl(il, (lane & 48) + g * 4 + e);
        int s = qw + n * 16 + g * 4 + e;
#pragma unroll
        for (int hb = 0; hb < 4; ++hb) {
          int c = head * 64 + hb * 16 + r;
          Ob[(size_t)(batch * 2048 + s) * 1024 + c] = f2bf(o[n][hb][e] * bv);
        }
      }
    }
  }
}

// ---------- launch ----------
extern "C" void kernel_launch(void* const* d_in, const int* in_sizes, int n_in,
                              void* d_out, int out_size, void* d_ws, size_t ws_size,
                              hipStream_t stream) {
  const float* x    = (const float*)d_in[0];   // [4,2048,1024]
  const float* Wqkv = (const float*)d_in[1];   // [1024,3072]
  const float* bqkv = (const float*)d_in[2];   // [3072]
  const float* Wout = (const float*)d_in[3];   // [1024,1024]
  const float* bout = (const float*)d_in[4];   // [1024]
  float* out = (float*)d_out;

  char* ws = (char*)d_ws;
  short* Xb    = (short*)(ws);                          // 16 MB (reused as attn-out)
  short* Wqkvb = (short*)(ws + ((size_t)16 << 20));     // 6 MB
  short* Woutb = (short*)(ws + ((size_t)22 << 20));     // 2 MB
  short* Qb    = (short*)(ws + ((size_t)24 << 20));     // 16 MB
  short* Kb    = (short*)(ws + ((size_t)40 << 20));     // 16 MB
  short* Vb    = (short*)(ws + ((size_t)56 << 20));     // 16 MB (V^T per head)

  cvt_f32_bf16<<<2048, 256, 0, stream>>>(x, Xb, 4 * 2048 * 1024);
  cvt_f32_bf16<<<1024, 256, 0, stream>>>(Wqkv, Wqkvb, 1024 * 3072);
  cvt_f32_bf16<<<512, 256, 0, stream>>>(Wout, Woutb, 1024 * 1024);

  gemm_qkv<<<64 * 24, 256, 0, stream>>>(Xb, Wqkvb, bqkv, Qb, Kb, Vb);
  attn<<<512, 256, 0, stream>>>(Qb, Kb, Vb, Xb);
  gemm_out<<<64 * 8, 256, 0, stream>>>(Xb, Woutb, bout, out);
}